// Round 6
// baseline (2284.733 us; speedup 1.0000x reference)
//
#include <hip/hip_runtime.h>
#include <cstddef>

// SpectralPredictor: Z=200 independent band-chains, each a strictly sequential
// 36864-step raster recurrence with 4-float weight state.
// ROUND-5 MAPPING: lane = band (throughput, not latency).
//   13 blocks x 16 bands. Per block: wave0 = chain wave, lane zl runs band
//   z0+zl's recurrence entirely in-lane (12 VALU/step, no cross-lane ops).
//   Waves 1-3 = stagers: transpose-load {N,cur,sp,c1..c4} into band-major LDS
//   (48B band stride -> chain reads 2-way/free, transposed writes ~6-way min),
//   and drain outputs (pred=clip(cur-res), res) from the res ring.
//   Double-buffered K=32-step batches, one barrier per batch.

#define Zb 200
#define Yd 192
#define Xd 192
#define Pb 15
#define WN 19
#define BB 16                    // bands per block
#define KK 32                    // steps per batch
#define NBATCH ((Yd * Xd) / KK)  // 1152

typedef float f4 __attribute__((ext_vector_type(4)));

__global__ __launch_bounds__(256, 1)
void spectral_predict(const float* __restrict__ img,
                      const float* __restrict__ w0buf,
                      float* __restrict__ outp) {
  const int z0   = blockIdx.x * BB;
  const int Bact = (Zb - z0 < BB) ? (Zb - z0) : BB;
  const int wv   = threadIdx.x >> 6;
  const int lane = threadIdx.x & 63;

  // pack[buf][s][z][12]: floats {N,cur,sp,c1, c2,c3,c4,pad, 4x pad}
  // band stride 48B => chain b128 reads hit quads 3*z%8 (2-way, free);
  // stager transposed writes spread over all 8 quads (~6-way = min pipe).
  __shared__ float pack[2][KK][BB][12];   // 49152 B
  __shared__ float resr[2][KK][17];       // 4352 B; stride 17 => conflict-free both ways

  const size_t YX  = (size_t)Yd * Xd;
  const size_t ZYX = (size_t)Zb * YX;

  if (wv == 0) {
    // ---------------- chain wave: lane zl = band z0+zl ----------------
    const int zl = lane & 15;
    const int zc = (zl < Bact) ? zl : (Bact - 1);
    const int zg = z0 + zc;                      // clamped for safe loads
    float w0 = w0buf[zg * WN + 0];
    float w1 = w0buf[zg * WN + 1];
    float w2 = w0buf[zg * WN + 2];
    float w3 = w0buf[zg * WN + 3];
    float resP = 0.f, c1p = 0.f, c2p = 0.f, c3p = 0.f, c4p = 0.f;
    float sW = 0.f, sNW = 0.f;

    __syncthreads();                             // wait for fill(0)
    for (int p = 0; p < NBATCH; ++p) {
      const int b = p & 1;
      if ((p % 6) == 0) { sW = 0.f; sNW = 0.f; } // x0==0: W/NW border zeros
      if (lane < BB) {
        f4 Ar[KK + 4], Br[KK + 4];               // compile-time indices only
#pragma unroll
        for (int s = 0; s < 4; ++s) {            // software skew = 4 steps
          Ar[s] = *(const f4*)&pack[b][s][zl][0];
          Br[s] = *(const f4*)&pack[b][s][zl][4];
        }
#pragma unroll
        for (int s = 0; s < KK; ++s) {
          if (s + 4 < KK) {
            Ar[s + 4] = *(const f4*)&pack[b][s + 4][zl][0];
            Br[s + 4] = *(const f4*)&pack[b][s + 4][zl][4];
          }
          const f4 A  = Ar[s];                   // {N, cur, sp, c1}
          const f4 Bv = Br[s];                   // {c2, c3, c4, pad}
          // apply previous step's update first (re-indexed recurrence)
          w0 = __builtin_amdgcn_fmed3f(__builtin_fmaf(resP, c1p, w0), -1.f, 1.f);
          w1 = __builtin_amdgcn_fmed3f(__builtin_fmaf(resP, c2p, w1), -1.f, 1.f);
          w2 = __builtin_amdgcn_fmed3f(__builtin_fmaf(resP, c3p, w2), -1.f, 1.f);
          w3 = __builtin_amdgcn_fmed3f(__builtin_fmaf(resP, c4p, w3), -1.f, 1.f);
          float acc = __builtin_fmaf(-w0, A.x, A.y);   // cur - w0*N
          acc = __builtin_fmaf(-w1, sW,  acc);
          acc = __builtin_fmaf(-w2, sNW, acc);
          const float res = __builtin_fmaf(-w3, A.z, acc);
          resr[b][s][zl] = res;
          resP = res; c1p = A.w; c2p = Bv.x; c3p = Bv.y; c4p = Bv.z;
          sW = A.y; sNW = A.x;
        }
      }
      __syncthreads();
    }
  } else {
    // ---------------- stager waves (wv = 1..3) ----------------
    const int sw = wv - 1;        // 0..2
    const int hl = lane >> 5;     // half-wave: 2 bands per wave-pass
    const int l  = lane & 31;     // step within batch

    auto fill = [&](int pp) {
      const int bb = pp & 1;
      const int y  = pp / 6;
      const int x0 = (pp % 6) * KK;
      const int x  = x0 + l;
#pragma unroll
      for (int j = 0; j < 3; ++j) {
        const int zpair = sw + j * 3;            // 0..8; pairs 0..7 used
        const int zl = zpair * 2 + hl;
        if (zpair < 8 && zl < Bact) {
          const int zg = z0 + zl;
          const int zp = (zg - Pb > 0) ? (zg - Pb) : 0;
          const float* bandp = img + (size_t)zg * YX + (size_t)y * Xd;
          const float cur = bandp[x];
          const float Nv  = (y > 0) ? bandp[x - Xd] : 0.f;
          const float Wv  = (x > 0) ? bandp[x - 1] : 0.f;
          const float NWv = (y > 0 && x > 0) ? bandp[x - Xd - 1] : 0.f;
          const float sp  = (zg > 0) ? img[(size_t)zp * YX + (size_t)y * Xd + x] : 0.f;
          const float d1 = Nv - Wv;
          const float d2 = Wv - NWv;
          const float d3 = NWv - Nv;
          const float d4 = (Nv + Wv) - 2.f * NWv;
          const float c1 = (0.01f * d1) / (fabsf(d1) + 1e-8f);
          const float c2 = (0.01f * d2) / (fabsf(d2) + 1e-8f);
          const float c3 = (0.01f * d3) / (fabsf(d3) + 1e-8f);
          const float c4 = (0.01f * d4) / (fabsf(d4) + 1e-8f);
          *(f4*)&pack[bb][l][zl][0] = f4{Nv, cur, sp, c1};
          *(f4*)&pack[bb][l][zl][4] = f4{c2, c3, c4, 0.f};
        }
      }
    };

    auto drain = [&](int pd) {
      const int bd = pd & 1;
      const int t0 = pd * KK;
#pragma unroll
      for (int j = 0; j < 3; ++j) {
        const int zpair = sw + j * 3;
        const int zl = zpair * 2 + hl;
        if (zpair < 8 && zl < Bact) {
          const int zg = z0 + zl;
          const float res = resr[bd][l][zl];
          const float cur = img[(size_t)zg * YX + t0 + l];
          float pred = cur - res;                // clip never binds on dot; clamp anyway
          pred = __builtin_amdgcn_fmed3f(pred, -32768.f, 32767.f);
          outp[(size_t)zg * YX + t0 + l] = pred;
          outp[ZYX + (size_t)zg * YX + t0 + l] = res;
        }
      }
    };

    fill(0);
    __syncthreads();
    for (int p = 0; p < NBATCH; ++p) {
      if (p >= 1) drain(p - 1);                  // drain ring slot (p-1)&1
      if (p + 1 < NBATCH) fill(p + 1);           // fill buf (p+1)&1
      __syncthreads();
    }
    drain(NBATCH - 1);
  }
}

extern "C" void kernel_launch(void* const* d_in, const int* in_sizes, int n_in,
                              void* d_out, int out_size, void* d_ws, size_t ws_size,
                              hipStream_t stream) {
  const float* img = (const float*)d_in[0];
  const float* w0  = (const float*)d_in[1];
  float* out = (float*)d_out;
  const int nblocks = (Zb + BB - 1) / BB;        // 13
  hipLaunchKernelGGL(spectral_predict, dim3(nblocks), dim3(256), 0, stream,
                     img, w0, out);
}

// Round 7
// 1622.234 us; speedup vs baseline: 1.4084x; 1.4084x over previous
//
#include <hip/hip_runtime.h>
#include <cstddef>

// SpectralPredictor: Z=200 bands, independent sequential 36864-step raster
// recurrence, 4-float weight state. weights0==0 => only w[0..3] live, only
// sp[0]=image[max(z-15,0),y,x] matters.
// Block = 1 band, 2 waves:
//   wave0 = chain. Inline-asm enforced pipeline: ds_read_b128 pairs issued
//     7 steps ahead (asm volatile, cannot be sunk), consumption gated by
//     counted "s_waitcnt lgkmcnt(12)" that PINS the consumed regs via "+v".
//     Chain issues NO other lgkm ops (counting stays exact); outputs are
//     stored directly to global by lane 0 (vmcnt, fire-and-forget).
//   wave1 = stager: fills pack rows {N,cur,sp,c1..c4} (exact f32 divides).

#define Zb 200
#define Yd 192
#define Xd 192
#define Pb 15
#define WN 19

typedef float f4 __attribute__((ext_vector_type(4)));

#define STR2(x) #x
#define STR(x) STR2(x)

// -- chain-step machinery (J = step mod 8, JP = (J+7)&7 = refill slot) --
#define WAITPIN(J, CNT) \
  asm volatile("s_waitcnt lgkmcnt(" STR(CNT) ")" : "+v"(rA##J), "+v"(rB##J));

#define ISSUE(J, JP) \
  asm volatile("ds_read_b128 %0, %2 offset:%3\n\tds_read_b128 %1, %2 offset:%4" \
               : "=v"(rA##JP), "=v"(rB##JP) \
               : "v"(lpa), "i"((J + 7) * 32), "i"((J + 7) * 32 + 16));

#define PRO(S) \
  asm volatile("ds_read_b128 %0, %2 offset:%3\n\tds_read_b128 %1, %2 offset:%4" \
               : "=v"(rA##S), "=v"(rB##S) \
               : "v"(rowa), "i"((S) * 32), "i"((S) * 32 + 16));

#define CONSUME(J)                                                            \
  {                                                                           \
    const float Nv = rA##J.x, cu = rA##J.y, sp = rA##J.z;                     \
    w0 = __builtin_amdgcn_fmed3f(__builtin_fmaf(resP, c1p, w0), -1.f, 1.f);   \
    w1 = __builtin_amdgcn_fmed3f(__builtin_fmaf(resP, c2p, w1), -1.f, 1.f);   \
    w2 = __builtin_amdgcn_fmed3f(__builtin_fmaf(resP, c3p, w2), -1.f, 1.f);   \
    w3 = __builtin_amdgcn_fmed3f(__builtin_fmaf(resP, c4p, w3), -1.f, 1.f);   \
    float acc = __builtin_fmaf(-w0, Nv, cu);                                  \
    acc = __builtin_fmaf(-w1, sW, acc);                                       \
    acc = __builtin_fmaf(-w2, sNW, acc);                                      \
    const float res = __builtin_fmaf(-w3, sp, acc);                           \
    float pr = cu - res;                                                      \
    pr = fminf(fmaxf(pr, -32768.f), 32767.f);                                 \
    resP = res;                                                               \
    c1p = rA##J.w; c2p = rB##J.x; c3p = rB##J.y; c4p = rB##J.z;               \
    sW = cu; sNW = Nv;                                                        \
    rq[(J) & 3] = res; pq[(J) & 3] = pr;                                      \
  }

#define STOREQ()                                                              \
  {                                                                           \
    if (threadIdx.x == 0) {                                                   \
      f4 P = {pq[0], pq[1], pq[2], pq[3]};                                    \
      f4 R = {rq[0], rq[1], rq[2], rq[3]};                                    \
      *(f4*)(op + qoff) = P;                                                  \
      *(f4*)(orr + qoff) = R;                                                 \
    }                                                                         \
    qoff += 4;                                                                \
  }

#define STEP(J, JP) WAITPIN(J, 12) CONSUME(J) ISSUE(J, JP)

__global__ __launch_bounds__(128, 1)
void spectral_predict(const float* __restrict__ img,
                      const float* __restrict__ w0buf,
                      float* __restrict__ outp) {
  const int z    = blockIdx.x;
  const int wv   = threadIdx.x >> 6;
  const int lane = threadIdx.x & 63;

  // per-pixel pack: {N, cur, sp, c1, c2, c3, c4, pad}, 32 B/pixel
  __shared__ float pack[2][Xd * 8];   // 12 KiB

  const size_t YX  = (size_t)Yd * Xd;
  const size_t ZYX = (size_t)Zb * YX;
  const float* band = img + (size_t)z * YX;
  const int zp = (z - Pb) > 0 ? (z - Pb) : 0;
  const float* spb = img + (size_t)zp * YX;
  const float spmask = (z > 0) ? 1.0f : 0.0f;

  if (wv == 1) {
    // ---------------- stager: fill pack rows ----------------
    auto fill = [&](int yy) {
      float* dst = pack[yy & 1];
#pragma unroll
      for (int i = 0; i < 3; ++i) {
        const int x = i * 64 + lane;
        const float cur = band[yy * Xd + x];
        const float Nv  = (yy > 0) ? band[(yy - 1) * Xd + x] : 0.f;
        const float Wv  = (x > 0) ? band[yy * Xd + x - 1] : 0.f;
        const float NWv = (yy > 0 && x > 0) ? band[(yy - 1) * Xd + x - 1] : 0.f;
        const float sp  = spmask * spb[yy * Xd + x];
        const float d1 = Nv - Wv;
        const float d2 = Wv - NWv;
        const float d3 = NWv - Nv;
        const float d4 = (Nv + Wv) - 2.f * NWv;
        const float c1 = (0.01f * d1) / (fabsf(d1) + 1e-8f);
        const float c2 = (0.01f * d2) / (fabsf(d2) + 1e-8f);
        const float c3 = (0.01f * d3) / (fabsf(d3) + 1e-8f);
        const float c4 = (0.01f * d4) / (fabsf(d4) + 1e-8f);
        f4* dv = (f4*)(dst + (size_t)x * 8);
        dv[0] = f4{Nv, cur, sp, c1};
        dv[1] = f4{c2, c3, c4, 0.f};
      }
    };
    fill(0);
    __syncthreads();
    for (int y = 0; y < Yd; ++y) {
      if (y + 1 < Yd) fill(y + 1);
      __syncthreads();
    }
  } else {
    // ---------------- chain wave ----------------
    float w0 = w0buf[z * WN + 0];
    float w1 = w0buf[z * WN + 1];
    float w2 = w0buf[z * WN + 2];
    float w3 = w0buf[z * WN + 3];
    float resP = 0.f, c1p = 0.f, c2p = 0.f, c3p = 0.f, c4p = 0.f;

    __syncthreads();                       // row 0 staged
    for (int y = 0; y < Yd; ++y) {
      const unsigned rowa = (unsigned)(size_t)(&pack[y & 1][0]);
      float sW = 0.f, sNW = 0.f;           // x==0 border zeros
      float pq[4], rq[4];
      int qoff = 0;
      float* op  = outp + (size_t)z * YX + (size_t)y * Xd;
      float* orr = op + ZYX;

      f4 rA0{}, rA1{}, rA2{}, rA3{}, rA4{}, rA5{}, rA6{}, rA7{};
      f4 rB0{}, rB1{}, rB2{}, rB3{}, rB4{}, rB5{}, rB6{}, rB7{};

      // prologue: issue slots 0..6 (7 pairs, 14 lgkm events in flight)
      PRO(0) PRO(1) PRO(2) PRO(3) PRO(4) PRO(5) PRO(6)

      for (int k = 0; k < 23; ++k) {       // steps 8k..8k+7
        const unsigned lpa = rowa + (unsigned)k * 256u;
        STEP(0, 7) STEP(1, 0) STEP(2, 1) STEP(3, 2) STOREQ()
        STEP(4, 3) STEP(5, 4) STEP(6, 5) STEP(7, 6) STOREQ()
      }
      {                                    // k = 23 tail: steps 184..191
        const unsigned lpa = rowa + 23u * 256u;
        WAITPIN(0, 12) CONSUME(0) ISSUE(0, 7)   // target 191 = slot 7
        WAITPIN(1, 12) CONSUME(1)
        WAITPIN(2, 10) CONSUME(2)
        WAITPIN(3, 8)  CONSUME(3) STOREQ()
        WAITPIN(4, 6)  CONSUME(4)
        WAITPIN(5, 4)  CONSUME(5)
        WAITPIN(6, 2)  CONSUME(6)
        WAITPIN(7, 0)  CONSUME(7) STOREQ()      // lgkmcnt(0): clean slate
      }
      // raw barrier: chain has no pending lgkm (wait(0) above); avoids the
      // compiler's full vmcnt(0) drain of our fire-and-forget stores.
      asm volatile("s_barrier" ::: "memory");
    }
  }
}

extern "C" void kernel_launch(void* const* d_in, const int* in_sizes, int n_in,
                              void* d_out, int out_size, void* d_ws, size_t ws_size,
                              hipStream_t stream) {
  const float* img = (const float*)d_in[0];
  const float* w0  = (const float*)d_in[1];
  float* out = (float*)d_out;
  hipLaunchKernelGGL(spectral_predict, dim3(Zb), dim3(128), 0, stream,
                     img, w0, out);
}

// Round 9
// 1464.090 us; speedup vs baseline: 1.5605x; 1.1080x over previous
//
#include <hip/hip_runtime.h>
#include <cstddef>

// SpectralPredictor: Z=200 bands, independent sequential 36864-step raster
// recurrence, 4-float weight state. weights0==0 => only w[0..3] live, only
// sp[0]=image[max(z-15,0),y,x] matters.
// Round-8: chain row-loop is ONE self-contained asm block (fixed clobbered
// regs v64-v108) so the compiler can never copy/remat an in-flight ds_read
// destination (the round-7 failure mode). Depth-1-quad pipeline, uniform
// s_waitcnt lgkmcnt(8) (first quad 7), peak 12 outstanding (<=15, 4-bit cnt).
// Layout per row buffer (7936 B): [pack: 192*32B slots {A=N,W,NW,sp | B=c's
// of PREVIOUS pixel}][curb: 192 f32][resr: 192 f32][pad].
// wave1 stager fills pack/curb and drains (pred=clamp(cur-res), res).

#define Zb 200
#define Yd 192
#define Xd 192
#define Pb 15
#define WN 19

typedef float f4 __attribute__((ext_vector_type(4)));

// step t: wait; w += res_{t-1}*c_{t-1} (B); clamp; res = cur - dot(w, A); stash
#define CSTEP(A0,A1,A2,A3,B0,B1,B2,B3,CQ,RR,O1,O2,W) \
  "s_waitcnt lgkmcnt(" #W ")\n\t" \
  "v_fma_f32 %[w0], %[rp], v" #B0 ", %[w0]\n\t" \
  "v_fma_f32 %[w1], %[rp], v" #B1 ", %[w1]\n\t" \
  "v_fma_f32 %[w2], %[rp], v" #B2 ", %[w2]\n\t" \
  "v_fma_f32 %[w3], %[rp], v" #B3 ", %[w3]\n\t" \
  "v_med3_f32 %[w0], %[w0], -1.0, 1.0\n\t" \
  "v_med3_f32 %[w1], %[w1], -1.0, 1.0\n\t" \
  "v_med3_f32 %[w2], %[w2], -1.0, 1.0\n\t" \
  "v_med3_f32 %[w3], %[w3], -1.0, 1.0\n\t" \
  "v_fma_f32 %[rp], -%[w0], v" #A0 ", v" #CQ "\n\t" \
  "v_fma_f32 %[rp], -%[w1], v" #A1 ", %[rp]\n\t" \
  "v_fma_f32 %[rp], -%[w2], v" #A2 ", %[rp]\n\t" \
  "v_fma_f32 %[rp], -%[w3], v" #A3 ", %[rp]\n\t" \
  "v_mov_b32 v" #RR ", %[rp]\n\t" \
  "ds_read_b128 v[" #A0 ":" #A3 "], %[pa] offset:" #O1 "\n\t" \
  "ds_read_b128 v[" #B0 ":" #B3 "], %[pa] offset:" #O2 "\n\t"

// quad: prefetch next cur-quad into other cq set; 4 steps; ring write; advance
#define CQUAD(PF0,PF3,CQ0,CQ1,CQ2,CQ3,W) \
  "ds_read_b128 v[" #PF0 ":" #PF3 "], %[ca] offset:16\n\t" \
  CSTEP(64,65,66,67,68,69,70,71,CQ0,104,128,144,W) \
  CSTEP(72,73,74,75,76,77,78,79,CQ1,105,160,176,W) \
  CSTEP(80,81,82,83,84,85,86,87,CQ2,106,192,208,W) \
  CSTEP(88,89,90,91,92,93,94,95,CQ3,107,224,240,W) \
  "ds_write_b128 %[ca], v[104:107] offset:768\n\t" \
  "v_add_u32 %[pa], 0x80, %[pa]\n\t" \
  "v_add_u32 %[ca], 16, %[ca]\n\t"

__global__ __launch_bounds__(128, 1)
void spectral_predict(const float* __restrict__ img,
                      const float* __restrict__ w0buf,
                      float* __restrict__ outp) {
  const int z    = blockIdx.x;
  const int wv   = threadIdx.x >> 6;
  const int lane = threadIdx.x & 63;

  __shared__ __align__(16) float region[2][1984];  // pack|curb|resr|pad

  const size_t YX  = (size_t)Yd * Xd;
  const size_t ZYX = (size_t)Zb * YX;
  const float* band = img + (size_t)z * YX;
  const int zp = (z - Pb) > 0 ? (z - Pb) : 0;
  const float* spb = img + (size_t)zp * YX;
  const float spmask = (z > 0) ? 1.0f : 0.0f;

  if (wv == 1) {
    // ---------------- stager ----------------
    auto fill = [&](int yy) {
      float* pk = &region[yy & 1][0];
      float* cb = &region[yy & 1][1536];
      const float* brow  = band + yy * Xd;
      const float* brow1 = band + (yy - 1) * Xd;   // deref'd only if yy>0
      const float* sprow = spb + yy * Xd;
#pragma unroll
      for (int i = 0; i < 3; ++i) {
        const int x = i * 64 + lane;
        const float cur = brow[x];
        const float Nv  = (yy > 0) ? brow1[x] : 0.f;
        const float Wv  = (x > 0) ? brow[x - 1] : 0.f;
        const float NWv = (yy > 0 && x > 0) ? brow1[x - 1] : 0.f;
        const float sp  = spmask * sprow[x];
        *(f4*)(pk + (size_t)x * 8) = f4{Nv, Wv, NWv, sp};
        cb[x] = cur;
        const float d1 = Nv - Wv, d2 = Wv - NWv, d3 = NWv - Nv;
        const float d4 = (Nv + Wv) - 2.f * NWv;
        const float c1 = (0.01f * d1) / (fabsf(d1) + 1e-8f);
        const float c2 = (0.01f * d2) / (fabsf(d2) + 1e-8f);
        const float c3 = (0.01f * d3) / (fabsf(d3) + 1e-8f);
        const float c4 = (0.01f * d4) / (fabsf(d4) + 1e-8f);
        if (x < Xd - 1) *(f4*)(pk + (size_t)(x + 1) * 8 + 4) = f4{c1, c2, c3, c4};
      }
      if (lane == 0) {   // B of slot 0 = c's of pixel (yy-1, 191)
        f4 cb0 = f4{0.f, 0.f, 0.f, 0.f};
        if (yy > 0) {
          const float Np  = (yy >= 2) ? band[(yy - 2) * Xd + (Xd - 1)] : 0.f;
          const float Wp  = band[(yy - 1) * Xd + (Xd - 2)];
          const float NWp = (yy >= 2) ? band[(yy - 2) * Xd + (Xd - 2)] : 0.f;
          const float e1 = Np - Wp, e2 = Wp - NWp, e3 = NWp - Np;
          const float e4 = (Np + Wp) - 2.f * NWp;
          cb0 = f4{(0.01f * e1) / (fabsf(e1) + 1e-8f),
                   (0.01f * e2) / (fabsf(e2) + 1e-8f),
                   (0.01f * e3) / (fabsf(e3) + 1e-8f),
                   (0.01f * e4) / (fabsf(e4) + 1e-8f)};
        }
        *(f4*)(pk + 4) = cb0;
      }
    };

    auto drain = [&](int yy) {
      const float* rg = &region[yy & 1][1728];
      const float* cb = &region[yy & 1][1536];
      float* op  = outp + (size_t)z * YX + (size_t)yy * Xd;
      float* orr = op + ZYX;
#pragma unroll
      for (int i = 0; i < 3; ++i) {
        const int x = i * 64 + lane;
        const float res = rg[x];
        const float cur = cb[x];
        const float pred = __builtin_amdgcn_fmed3f(cur - res, -32768.f, 32767.f);
        op[x]  = pred;
        orr[x] = res;
      }
    };

    fill(0);
    __syncthreads();
    for (int y = 0; y < Yd; ++y) {
      if (y >= 1) drain(y - 1);          // in-wave DS order: reads before refill
      if (y + 1 < Yd) fill(y + 1);
      __syncthreads();
    }
    drain(Yd - 1);
  } else {
    // ---------------- chain wave ----------------
    float w0_ = w0buf[z * WN + 0];
    float w1_ = w0buf[z * WN + 1];
    float w2_ = w0buf[z * WN + 2];
    float w3_ = w0buf[z * WN + 3];
    float rp_ = 0.f;

    __syncthreads();                     // row 0 staged
    for (int y = 0; y < Yd; ++y) {
      unsigned pa = (unsigned)(size_t)&region[y & 1][0];
      unsigned ca = pa + 6144u;
      asm volatile(
        // prologue: cur quad 0 -> set0; slots 0..3 (steps 0..3)  [9 events]
        "ds_read_b128 v[96:99], %[ca]\n\t"
        "ds_read_b128 v[64:67], %[pa]\n\t"
        "ds_read_b128 v[68:71], %[pa] offset:16\n\t"
        "ds_read_b128 v[72:75], %[pa] offset:32\n\t"
        "ds_read_b128 v[76:79], %[pa] offset:48\n\t"
        "ds_read_b128 v[80:83], %[pa] offset:64\n\t"
        "ds_read_b128 v[84:87], %[pa] offset:80\n\t"
        "ds_read_b128 v[88:91], %[pa] offset:96\n\t"
        "ds_read_b128 v[92:95], %[pa] offset:112\n\t"
        CQUAD(100,103, 96,97,98,99, 7)   // quad 0 (even): first-quad waits=7
        "v_mov_b32 v108, 0\n\t"
        "9:\n\t"
        CQUAD(96,99, 100,101,102,103, 8) // odd quad
        CQUAD(100,103, 96,97,98,99, 8)   // even quad
        "v_add_u32 v108, 1, v108\n\t"
        "v_cmp_gt_u32 vcc, 23, v108\n\t"
        "s_cbranch_vccnz 9b\n\t"
        CQUAD(96,99, 100,101,102,103, 8) // quad 47 (odd)
        "s_waitcnt lgkmcnt(0)\n\t"
        : [w0]"+v"(w0_), [w1]"+v"(w1_), [w2]"+v"(w2_), [w3]"+v"(w3_),
          [rp]"+v"(rp_), [pa]"+v"(pa), [ca]"+v"(ca)
        :
        : "v64","v65","v66","v67","v68","v69","v70","v71",
          "v72","v73","v74","v75","v76","v77","v78","v79",
          "v80","v81","v82","v83","v84","v85","v86","v87",
          "v88","v89","v90","v91","v92","v93","v94","v95",
          "v96","v97","v98","v99","v100","v101","v102","v103",
          "v104","v105","v106","v107","v108","vcc","memory");
      __syncthreads();
    }
  }
}

extern "C" void kernel_launch(void* const* d_in, const int* in_sizes, int n_in,
                              void* d_out, int out_size, void* d_ws, size_t ws_size,
                              hipStream_t stream) {
  const float* img = (const float*)d_in[0];
  const float* w0  = (const float*)d_in[1];
  float* out = (float*)d_out;
  hipLaunchKernelGGL(spectral_predict, dim3(Zb), dim3(128), 0, stream,
                     img, w0, out);
}

// Round 10
// 1260.352 us; speedup vs baseline: 1.8128x; 1.1617x over previous
//
#include <hip/hip_runtime.h>
#include <cstddef>

// SpectralPredictor: Z=200 bands, independent sequential 36864-step raster
// recurrence, 4-float weight state. weights0==0 => only w[0..3] live, only
// sp[0]=image[max(z-15,0),y,x] matters.
// Round-9: minimum-instruction asm chain (15.2 instr/step):
//  - rotating res regs (no mov); cur_t taken from A_{t+1}.y in the pipeline
//    (stager stages a 193rd slot holding cur_191); one wait per 2 steps;
//    ring writes 3xb128 per 12 steps under exec toggle, double-buffered
//    res halves (WAR-safe vs in-flight ds_write).
//  - 6-slot register pipeline (banks v64..v111), res v112..v135.
//  - wait algebra (in-order DS retirement): steady pairs lgkmcnt(7);
//    first two pairs after a 3-write burst: lgkmcnt(10); peak 14 <= 15.
// wave1 stager: pack A={N,W,NW,sp}, B={c's of previous pixel}; curb; drain.

#define Zb 200
#define Yd 192
#define Xd 192
#define Pb 15
#define WN 19

typedef float f4 __attribute__((ext_vector_type(4)));

#define RD1(D0,D3,OFF) \
  "ds_read_b128 v[" #D0 ":" #D3 "], %[pa] offset:" #OFF "\n\t"
#define WT(N) "s_waitcnt lgkmcnt(" #N ")\n\t"

// one step: 4 upd-fma, 4 med3, 4 res-fma (res starts from CU = A_{t+1}.y)
#define CST(RPS,RR,A0,A1,A2,A3,B0,B1,B2,B3,CU) \
  "v_fma_f32 %[w0], " RPS ", v" #B0 ", %[w0]\n\t" \
  "v_fma_f32 %[w1], " RPS ", v" #B1 ", %[w1]\n\t" \
  "v_fma_f32 %[w2], " RPS ", v" #B2 ", %[w2]\n\t" \
  "v_fma_f32 %[w3], " RPS ", v" #B3 ", %[w3]\n\t" \
  "v_med3_f32 %[w0], %[w0], -1.0, 1.0\n\t" \
  "v_med3_f32 %[w1], %[w1], -1.0, 1.0\n\t" \
  "v_med3_f32 %[w2], %[w2], -1.0, 1.0\n\t" \
  "v_med3_f32 %[w3], %[w3], -1.0, 1.0\n\t" \
  "v_fma_f32 v" #RR ", -%[w0], v" #A0 ", v" #CU "\n\t" \
  "v_fma_f32 v" #RR ", -%[w1], v" #A1 ", v" #RR "\n\t" \
  "v_fma_f32 v" #RR ", -%[w2], v" #A2 ", v" #RR "\n\t" \
  "v_fma_f32 v" #RR ", -%[w3], v" #A3 ", v" #RR "\n\t"

// pair at bank-position 0 (banks 0,1), 1 (banks 2,3), 2 (banks 4,5)
#define PAIRB0(WN_,RPS,Ra,Rb,OA,OB,OC,OD) \
  WT(WN_) \
  CST(RPS, Ra, 64,65,66,67, 68,69,70,71, 73) \
  CST("v" #Ra, Rb, 72,73,74,75, 76,77,78,79, 81) \
  RD1(64,67,OA) RD1(68,71,OB) RD1(72,75,OC) RD1(76,79,OD)
#define PAIRB1(WN_,RPS,Ra,Rb,OA,OB,OC,OD) \
  WT(WN_) \
  CST(RPS, Ra, 80,81,82,83, 84,85,86,87, 89) \
  CST("v" #Ra, Rb, 88,89,90,91, 92,93,94,95, 97) \
  RD1(80,83,OA) RD1(84,87,OB) RD1(88,91,OC) RD1(92,95,OD)
#define PAIRB2(WN_,RPS,Ra,Rb,OA,OB,OC,OD) \
  WT(WN_) \
  CST(RPS, Ra, 96,97,98,99, 100,101,102,103, 105) \
  CST("v" #Ra, Rb, 104,105,106,107, 108,109,110,111, 65) \
  RD1(96,99,OA) RD1(100,103,OB) RD1(104,107,OC) RD1(108,111,OD)

#define ITER_TAIL "v_add_u32 %[pa], 0x180, %[pa]\n\t"

#define ITER0 \
  PAIRB0(7,"%[rp]",112,113,192,208,224,240) \
  PAIRB1(7,"v113",114,115,256,272,288,304) \
  PAIRB2(7,"v115",116,117,320,336,352,368) \
  PAIRB0(7,"v117",118,119,384,400,416,432) \
  PAIRB1(7,"v119",120,121,448,464,480,496) \
  PAIRB2(7,"v121",122,123,512,528,544,560) \
  ITER_TAIL
#define ITER_P1 \
  PAIRB0(10,"v123",124,125,192,208,224,240) \
  PAIRB1(10,"v125",126,127,256,272,288,304) \
  PAIRB2(7,"v127",128,129,320,336,352,368) \
  PAIRB0(7,"v129",130,131,384,400,416,432) \
  PAIRB1(7,"v131",132,133,448,464,480,496) \
  PAIRB2(7,"v133",134,135,512,528,544,560) \
  ITER_TAIL
#define ITER_P0 \
  PAIRB0(10,"v135",112,113,192,208,224,240) \
  PAIRB1(10,"v113",114,115,256,272,288,304) \
  PAIRB2(7,"v115",116,117,320,336,352,368) \
  PAIRB0(7,"v117",118,119,384,400,416,432) \
  PAIRB1(7,"v119",120,121,448,464,480,496) \
  PAIRB2(7,"v121",122,123,512,528,544,560) \
  ITER_TAIL

#define WRT_A \
  "s_mov_b64 exec, 1\n\t" \
  "ds_write_b128 %[ca], v[112:115]\n\t" \
  "ds_write_b128 %[ca], v[116:119] offset:16\n\t" \
  "ds_write_b128 %[ca], v[120:123] offset:32\n\t" \
  "s_mov_b64 exec, -1\n\t" \
  "v_add_u32 %[ca], 48, %[ca]\n\t"
#define WRT_B \
  "s_mov_b64 exec, 1\n\t" \
  "ds_write_b128 %[ca], v[124:127]\n\t" \
  "ds_write_b128 %[ca], v[128:131] offset:16\n\t" \
  "ds_write_b128 %[ca], v[132:135] offset:32\n\t" \
  "s_mov_b64 exec, -1\n\t" \
  "v_add_u32 %[ca], 48, %[ca]\n\t"

__global__ __launch_bounds__(128, 1)
void spectral_predict(const float* __restrict__ img,
                      const float* __restrict__ w0buf,
                      float* __restrict__ outp) {
  const int z    = blockIdx.x;
  const int wv   = threadIdx.x >> 6;
  const int lane = threadIdx.x & 63;

  // per buffer (floats): [0,1600) pack = 200 slots x 32B (192 real + cur-ext
  // slot 192 + 7 pad); [1600,1792) curb; [1792,1984) resr.
  __shared__ __align__(16) float region[2][1984];   // 15872 B

  const size_t YX  = (size_t)Yd * Xd;
  const size_t ZYX = (size_t)Zb * YX;
  const float* band = img + (size_t)z * YX;
  const int zp = (z - Pb) > 0 ? (z - Pb) : 0;
  const float* spb = img + (size_t)zp * YX;
  const float spmask = (z > 0) ? 1.0f : 0.0f;

  if (wv == 1) {
    // ---------------- stager ----------------
    auto fill = [&](int yy) {
      float* pk = &region[yy & 1][0];
      float* cb = &region[yy & 1][1600];
      const float* brow  = band + yy * Xd;
      const float* brow1 = band + (yy - 1) * Xd;   // deref'd only if yy>0
      const float* sprow = spb + yy * Xd;
#pragma unroll
      for (int i = 0; i < 3; ++i) {
        const int x = i * 64 + lane;
        const float cur = brow[x];
        const float Nv  = (yy > 0) ? brow1[x] : 0.f;
        const float Wv  = (x > 0) ? brow[x - 1] : 0.f;
        const float NWv = (yy > 0 && x > 0) ? brow1[x - 1] : 0.f;
        const float sp  = spmask * sprow[x];
        *(f4*)(pk + (size_t)x * 8) = f4{Nv, Wv, NWv, sp};
        cb[x] = cur;
        const float d1 = Nv - Wv, d2 = Wv - NWv, d3 = NWv - Nv;
        const float d4 = (Nv + Wv) - 2.f * NWv;
        const float c1 = (0.01f * d1) / (fabsf(d1) + 1e-8f);
        const float c2 = (0.01f * d2) / (fabsf(d2) + 1e-8f);
        const float c3 = (0.01f * d3) / (fabsf(d3) + 1e-8f);
        const float c4 = (0.01f * d4) / (fabsf(d4) + 1e-8f);
        if (x < Xd - 1) *(f4*)(pk + (size_t)(x + 1) * 8 + 4) = f4{c1, c2, c3, c4};
      }
      if (lane == 0) {   // B of slot 0 = c's of pixel (yy-1, 191)
        f4 cb0 = f4{0.f, 0.f, 0.f, 0.f};
        if (yy > 0) {
          const float Np  = (yy >= 2) ? band[(yy - 2) * Xd + (Xd - 1)] : 0.f;
          const float Wp  = band[(yy - 1) * Xd + (Xd - 2)];
          const float NWp = (yy >= 2) ? band[(yy - 2) * Xd + (Xd - 2)] : 0.f;
          const float e1 = Np - Wp, e2 = Wp - NWp, e3 = NWp - Np;
          const float e4 = (Np + Wp) - 2.f * NWp;
          cb0 = f4{(0.01f * e1) / (fabsf(e1) + 1e-8f),
                   (0.01f * e2) / (fabsf(e2) + 1e-8f),
                   (0.01f * e3) / (fabsf(e3) + 1e-8f),
                   (0.01f * e4) / (fabsf(e4) + 1e-8f)};
        }
        *(f4*)(pk + 4) = cb0;
      }
      if (lane == 2) {   // cur-extension slot 192: A.y = cur at (yy,191)
        *(f4*)(pk + 1536) = f4{0.f, brow[Xd - 1], 0.f, 0.f};
        *(f4*)(pk + 1540) = f4{0.f, 0.f, 0.f, 0.f};
      }
    };

    auto drain = [&](int yy) {
      const float* rg = &region[yy & 1][1792];
      const float* cb = &region[yy & 1][1600];
      float* op  = outp + (size_t)z * YX + (size_t)yy * Xd;
      float* orr = op + ZYX;
#pragma unroll
      for (int i = 0; i < 3; ++i) {
        const int x = i * 64 + lane;
        const float res = rg[x];
        const float cur = cb[x];
        const float pred = __builtin_amdgcn_fmed3f(cur - res, -32768.f, 32767.f);
        op[x]  = pred;
        orr[x] = res;
      }
    };

    fill(0);
    __syncthreads();
    for (int y = 0; y < Yd; ++y) {
      if (y >= 1) drain(y - 1);          // in-wave DS order: reads before refill
      if (y + 1 < Yd) fill(y + 1);
      __syncthreads();
    }
    drain(Yd - 1);
  } else {
    // ---------------- chain wave ----------------
    float w0_ = w0buf[z * WN + 0];
    float w1_ = w0buf[z * WN + 1];
    float w2_ = w0buf[z * WN + 2];
    float w3_ = w0buf[z * WN + 3];
    float rp_ = 0.f;

    __syncthreads();                     // row 0 staged
    for (int y = 0; y < Yd; ++y) {
      unsigned pa = (unsigned)(size_t)&region[y & 1][0];
      unsigned ca = pa + 7168u;          // resr byte offset
      asm volatile(
        // prologue: slots 0..5 into banks 0..5 (12 reads)
        RD1(64,67,0)    RD1(68,71,16)
        RD1(72,75,32)   RD1(76,79,48)
        RD1(80,83,64)   RD1(84,87,80)
        RD1(88,91,96)   RD1(92,95,112)
        RD1(96,99,128)  RD1(100,103,144)
        RD1(104,107,160) RD1(108,111,176)
        ITER0                            // iter 0 (no ring writes)
        "s_movk_i32 s20, 7\n\t"
        "8:\n\t"
        WRT_A ITER_P1                    // odd iters: write v112-123, res->v124-135
        WRT_B ITER_P0                    // even iters: write v124-135, res->v112-123
        "s_sub_u32 s20, s20, 1\n\t"
        "s_cmp_lg_u32 s20, 0\n\t"
        "s_cbranch_scc1 8b\n\t"
        WRT_A ITER_P1                    // iter 15
        WRT_B                            // final ring batch
        WT(0)
        "v_mov_b32 %[rp], v135\n\t"      // carry res across rows via operand
        : [w0]"+v"(w0_), [w1]"+v"(w1_), [w2]"+v"(w2_), [w3]"+v"(w3_),
          [rp]"+v"(rp_), [pa]"+v"(pa), [ca]"+v"(ca)
        :
        : "v64","v65","v66","v67","v68","v69","v70","v71",
          "v72","v73","v74","v75","v76","v77","v78","v79",
          "v80","v81","v82","v83","v84","v85","v86","v87",
          "v88","v89","v90","v91","v92","v93","v94","v95",
          "v96","v97","v98","v99","v100","v101","v102","v103",
          "v104","v105","v106","v107","v108","v109","v110","v111",
          "v112","v113","v114","v115","v116","v117","v118","v119",
          "v120","v121","v122","v123","v124","v125","v126","v127",
          "v128","v129","v130","v131","v132","v133","v134","v135",
          "s20","scc","memory");
      __syncthreads();
    }
  }
}

extern "C" void kernel_launch(void* const* d_in, const int* in_sizes, int n_in,
                              void* d_out, int out_size, void* d_ws, size_t ws_size,
                              hipStream_t stream) {
  const float* img = (const float*)d_in[0];
  const float* w0  = (const float*)d_in[1];
  float* out = (float*)d_out;
  hipLaunchKernelGGL(spectral_predict, dim3(Zb), dim3(128), 0, stream,
                     img, w0, out);
}